// Round 2
// baseline (1922.554 us; speedup 1.0000x reference)
//
#include <hip/hip_runtime.h>
#include <hip/hip_bf16.h>

#define S_LEN 512
#define D_IN  64
#define HID   256
#define MLPH  64
#define D_OUT 16

// One workgroup (512 threads, 8 waves) per batch element. Weights live in
// registers: thread (r = tid&255, half = tid>>8) holds half of W_hh row r
// (128 fp32) + a chunk of W_ih row r (32 fp32); MLP chunks similarly.
// LDS holds only activations + partial sums (~9 KB).
__launch_bounds__(512, 2)
__global__ void rnn_ar_kernel(const float* __restrict__ x,
                              const float* __restrict__ W_ih,
                              const float* __restrict__ b_ih,
                              const float* __restrict__ W_hh,
                              const float* __restrict__ b_hh,
                              const float* __restrict__ W1,
                              const float* __restrict__ b1,
                              const float* __restrict__ W2,
                              const float* __restrict__ b2,
                              const float* __restrict__ W3,
                              const float* __restrict__ b3,
                              const int*   __restrict__ ps_ptr,
                              float* __restrict__ out) {
    const int b   = blockIdx.x;
    const int tid = threadIdx.x;
    const int ps  = *ps_ptr;

    __shared__ float s_xt[D_IN];        // current spliced input
    __shared__ float s_h[HID];          // hidden state
    __shared__ float s_part[2 * HID];   // RNN partials (2 K-halves)
    __shared__ float s_m1p[512];        // MLP1 partials
    __shared__ float s_a1[MLPH];
    __shared__ float s_m2p[512];        // MLP2 partials
    __shared__ float s_a2[MLPH];
    __shared__ float s_m3p[128];        // MLP3 partials

    const int r  = tid & 255;           // RNN output row
    const int h2 = tid >> 8;            // K-half (0/1)

    // ---- load register-resident weights (one-time; L2/L3-cached across wgs)
    float4 wih4[8];                     // W_ih[r, h2*32 .. +32)
    {
        const float4* s4 = (const float4*)(W_ih + (size_t)r * D_IN + h2 * 32);
        #pragma unroll
        for (int j = 0; j < 8; ++j) wih4[j] = s4[j];
    }
    float4 whh4[32];                    // W_hh[r, h2*128 .. +128)
    {
        const float4* s4 = (const float4*)(W_hh + (size_t)r * HID + h2 * 128);
        #pragma unroll
        for (int j = 0; j < 32; ++j) whh4[j] = s4[j];
    }
    float bias_h = 0.f;
    if (tid < HID) bias_h = b_ih[tid] + b_hh[tid];

    const int mr = tid & 63, mc = tid >> 6;   // MLP1/2: row, K-chunk (0..7)
    float4 w14[8];                      // W1[mr, mc*32 .. +32)
    {
        const float4* s4 = (const float4*)(W1 + (size_t)mr * HID + mc * 32);
        #pragma unroll
        for (int j = 0; j < 8; ++j) w14[j] = s4[j];
    }
    float4 w24[2];                      // W2[mr, mc*8 .. +8)
    {
        const float4* s4 = (const float4*)(W2 + (size_t)mr * MLPH + mc * 8);
        w24[0] = s4[0]; w24[1] = s4[1];
    }
    const int r3 = tid & 15, c3 = (tid >> 4) & 7;  // MLP3 (threads < 128)
    float4 w34[2] = {make_float4(0,0,0,0), make_float4(0,0,0,0)};
    if (tid < 128) {
        const float4* s4 = (const float4*)(W3 + (size_t)r3 * MLPH + c3 * 8);
        w34[0] = s4[0]; w34[1] = s4[1];
    }
    float bias1 = 0.f, bias2 = 0.f, bias3 = 0.f;
    if (tid < MLPH) { bias1 = b1[tid]; bias2 = b2[tid]; }
    if (tid < D_OUT) bias3 = b3[tid];

    if (tid < HID) s_h[tid] = 0.f;      // h0 = 0

    // prefetch x[b][0]
    float4 xcur = make_float4(0, 0, 0, 0);
    const float* xb = x + (size_t)b * S_LEN * D_IN;
    if (tid < 16) xcur = ((const float4*)xb)[tid];

    __syncthreads();

    for (int t = 0; t < S_LEN; ++t) {
        // ---- build xt (splice handled: o-writers already wrote s_xt[0:16]
        //      last step when t > ps; here we skip overwriting that region)
        if (tid < 16) {
            bool spliced = (t > ps) && (tid < 4);
            if (!spliced) ((float4*)s_xt)[tid] = xcur;
            int tn = (t + 1 < S_LEN) ? (t + 1) : (S_LEN - 1);
            xcur = ((const float4*)(xb + (size_t)tn * D_IN))[tid];  // prefetch
        }
        __syncthreads();   // B1: xt ready

        // ---- RNN partial: W_ih chunk + W_hh half-row (fp32 FMA)
        {
            float a0 = 0.f, a1 = 0.f, a2 = 0.f, a3 = 0.f;
            const float4* xv = (const float4*)(s_xt + h2 * 32);
            #pragma unroll
            for (int j = 0; j < 8; ++j) {
                float4 v = xv[j];
                a0 = fmaf(wih4[j].x, v.x, a0);
                a1 = fmaf(wih4[j].y, v.y, a1);
                a2 = fmaf(wih4[j].z, v.z, a2);
                a3 = fmaf(wih4[j].w, v.w, a3);
            }
            const float4* hv = (const float4*)(s_h + h2 * 128);
            #pragma unroll
            for (int j = 0; j < 32; ++j) {
                float4 v = hv[j];
                a0 = fmaf(whh4[j].x, v.x, a0);
                a1 = fmaf(whh4[j].y, v.y, a1);
                a2 = fmaf(whh4[j].z, v.z, a2);
                a3 = fmaf(whh4[j].w, v.w, a3);
            }
            s_part[tid] = (a0 + a1) + (a2 + a3);
        }
        __syncthreads();   // B2: RNN partials ready

        if (tid < HID) {
            float v = s_part[tid] + s_part[HID + tid] + bias_h;
            s_h[tid] = tanhf(v);
        }
        __syncthreads();   // B3: h ready

        // ---- MLP layer 1: 64 x 256
        {
            float a0 = 0.f, a1 = 0.f, a2 = 0.f, a3 = 0.f;
            const float4* hv = (const float4*)(s_h + mc * 32);
            #pragma unroll
            for (int j = 0; j < 8; ++j) {
                float4 v = hv[j];
                a0 = fmaf(w14[j].x, v.x, a0);
                a1 = fmaf(w14[j].y, v.y, a1);
                a2 = fmaf(w14[j].z, v.z, a2);
                a3 = fmaf(w14[j].w, v.w, a3);
            }
            s_m1p[tid] = (a0 + a1) + (a2 + a3);
        }
        __syncthreads();   // B4
        if (tid < MLPH) {
            float s = bias1;
            #pragma unroll
            for (int c = 0; c < 8; ++c) s += s_m1p[c * 64 + tid];
            s_a1[tid] = fmaxf(s, 0.f);
        }
        __syncthreads();   // B5: a1 ready

        // ---- MLP layer 2: 64 x 64
        {
            const float4* av = (const float4*)(s_a1 + mc * 8);
            float4 v0 = av[0], v1 = av[1];
            float a0 = fmaf(w24[0].x, v0.x, 0.f);
            a0 = fmaf(w24[0].y, v0.y, a0);
            a0 = fmaf(w24[0].z, v0.z, a0);
            a0 = fmaf(w24[0].w, v0.w, a0);
            float a1 = fmaf(w24[1].x, v1.x, 0.f);
            a1 = fmaf(w24[1].y, v1.y, a1);
            a1 = fmaf(w24[1].z, v1.z, a1);
            a1 = fmaf(w24[1].w, v1.w, a1);
            s_m2p[tid] = a0 + a1;
        }
        __syncthreads();   // B6
        if (tid < MLPH) {
            float s = bias2;
            #pragma unroll
            for (int c = 0; c < 8; ++c) s += s_m2p[c * 64 + tid];
            s_a2[tid] = fmaxf(s, 0.f);
        }
        __syncthreads();   // B7: a2 ready

        // ---- MLP layer 3: 16 x 64 (threads < 128)
        if (tid < 128) {
            const float4* av = (const float4*)(s_a2 + c3 * 8);
            float4 v0 = av[0], v1 = av[1];
            float a0 = fmaf(w34[0].x, v0.x, 0.f);
            a0 = fmaf(w34[0].y, v0.y, a0);
            a0 = fmaf(w34[0].z, v0.z, a0);
            a0 = fmaf(w34[0].w, v0.w, a0);
            float a1 = fmaf(w34[1].x, v1.x, 0.f);
            a1 = fmaf(w34[1].y, v1.y, a1);
            a1 = fmaf(w34[1].z, v1.z, a1);
            a1 = fmaf(w34[1].w, v1.w, a1);
            s_m3p[tid] = a0 + a1;
        }
        __syncthreads();   // B8
        if (tid < D_OUT) {
            float s = bias3;
            #pragma unroll
            for (int c = 0; c < 8; ++c) s += s_m3p[c * 16 + tid];
            out[((size_t)b * S_LEN + t) * D_OUT + tid] = s;
            // autoregressive splice for next step, written directly into xt.
            // Next step's builders skip [0:16] when (t+1) > ps, so no race;
            // next B1 orders this write vs. RNN readers.
            if (t + 1 > ps) s_xt[tid] = s;
        }
        // no barrier needed here: B1 of next iteration covers s_xt;
        // s_m3p etc. are rewritten only after further barriers.
    }
}

extern "C" void kernel_launch(void* const* d_in, const int* in_sizes, int n_in,
                              void* d_out, int out_size, void* d_ws, size_t ws_size,
                              hipStream_t stream) {
    (void)in_sizes; (void)n_in; (void)d_ws; (void)ws_size; (void)out_size;
    const float* x    = (const float*)d_in[0];
    const float* W_ih = (const float*)d_in[1];
    const float* bih  = (const float*)d_in[2];
    const float* W_hh = (const float*)d_in[3];
    const float* bhh  = (const float*)d_in[4];
    const float* W1   = (const float*)d_in[5];
    const float* b1   = (const float*)d_in[6];
    const float* W2   = (const float*)d_in[7];
    const float* b2   = (const float*)d_in[8];
    const float* W3   = (const float*)d_in[9];
    const float* b3   = (const float*)d_in[10];
    const int*   ps   = (const int*)d_in[11];
    float* out = (float*)d_out;

    rnn_ar_kernel<<<dim3(256), dim3(512), 0, stream>>>(
        x, W_ih, bih, W_hh, bhh, W1, b1, W2, b2, W3, b3, ps, out);
}